// Round 1
// baseline (1516.935 us; speedup 1.0000x reference)
//
#include <hip/hip_runtime.h>
#include <math.h>

#define B_    2
#define C_    1024
#define N_    80
#define D_    3074
#define DFF_  2048
#define OD_   1026      // C+2
#define QKV_  9222      // 3*D
#define M_    160       // B*N token rows
#define EPS_  1e-5f
#define KPD_  3104      // D_ rounded up to multiple of 32 (bf16 row stride)

typedef __attribute__((ext_vector_type(8))) short bf16x8;   // 8 bf16 = 4 VGPRs
typedef __attribute__((ext_vector_type(4))) float f32x4;

// fp32 -> bf16 (round-to-nearest-even), bit pattern as short
__device__ inline short f2bf(float f) {
    unsigned u = __float_as_uint(f);
    u += 0x7fffu + ((u >> 16) & 1u);
    return (short)(u >> 16);
}

// ---------------------------------------------------------------- reductions
__device__ inline float wave_sum(float v) {
#pragma unroll
    for (int off = 32; off > 0; off >>= 1) v += __shfl_down(v, off, 64);
    return v;
}

__device__ inline float wave_max(float v) {
#pragma unroll
    for (int off = 32; off > 0; off >>= 1) v = fmaxf(v, __shfl_down(v, off, 64));
    return v;
}

__device__ inline void block_reduce_2(float& s, float& s2, float* red) {
    int tid = threadIdx.x;
    int lane = tid & 63, wid = tid >> 6;
    s = wave_sum(s);
    s2 = wave_sum(s2);
    if (lane == 0) { red[wid] = s; red[4 + wid] = s2; }
    __syncthreads();
    if (tid == 0) {
        red[8] = red[0] + red[1] + red[2] + red[3];
        red[9] = red[4] + red[5] + red[6] + red[7];
    }
    __syncthreads();
    s = red[8]; s2 = red[9];
}

// ---------------------------------------------------------------- bilinear
__device__ inline void bilin_setup(int p, int& i0, int& i1, float& t) {
    float s = (p + 0.5f) * 0.0625f - 0.5f;
    s = fminf(fmaxf(s, 0.0f), 13.0f);
    i0 = (int)s;
    t = s - (float)i0;
    i1 = min(i0 + 1, 13);
}

__device__ inline float bilin_tap(const float* f, int y0, int y1, float ty,
                                  int x0, int x1, float tx) {
    float a = f[y0 * 14 + x0], b = f[y0 * 14 + x1];
    float c = f[y1 * 14 + x0], d = f[y1 * 14 + x1];
    return (1.f - ty) * ((1.f - tx) * a + tx * b) + ty * ((1.f - tx) * c + tx * d);
}

// ---------------------------------------------------------------- K0: align
__global__ __launch_bounds__(128) void align_kernel(const int* __restrict__ prev_b,
                                                    const int* __restrict__ first_b,
                                                    int* __restrict__ fb_al) {
    int b = blockIdx.x;
    int tid = threadIdx.x;
    __shared__ int dist[N_];
    __shared__ int bestIdx;
    if (tid < N_) {
        int s = 0;
        for (int j = 0; j < N_; ++j) {
            int src = (j - tid) % N_;
            if (src < 0) src += N_;
            int dy = prev_b[(b * N_ + j) * 2] - first_b[(b * N_ + src) * 2];
            int dx = prev_b[(b * N_ + j) * 2 + 1] - first_b[(b * N_ + src) * 2 + 1];
            s += abs(dy) + abs(dx);
        }
        dist[tid] = s;
    }
    __syncthreads();
    if (tid == 0) {
        int best = 0, bd = dist[0];
        for (int i = 1; i < N_; ++i)
            if (dist[i] < bd) { bd = dist[i]; best = i; }
        bestIdx = best;
    }
    __syncthreads();
    if (tid < N_) {
        int src = (tid - bestIdx) % N_;
        if (src < 0) src += N_;
        fb_al[(b * N_ + tid) * 2]     = first_b[(b * N_ + src) * 2];
        fb_al[(b * N_ + tid) * 2 + 1] = first_b[(b * N_ + src) * 2 + 1];
    }
}

// -------------------------------------------------- K1: pre_q/first_q gather
__global__ __launch_bounds__(256) void gather_init_kernel(
        const float* __restrict__ pre_f, const float* __restrict__ first_f,
        const int* __restrict__ prev_b, const int* __restrict__ fb_al,
        float* __restrict__ pre_q, float* __restrict__ first_q,
        float* __restrict__ curr) {
    int m = blockIdx.x;
    int b = m / N_;
    int tid = threadIdx.x;
    int py = prev_b[m * 2], px = prev_b[m * 2 + 1];
    int fy = fb_al[m * 2], fx = fb_al[m * 2 + 1];
    int py0, py1, px0, px1, fy0, fy1, fx0, fx1;
    float pty, ptx, fty, ftx;
    bilin_setup(py, py0, py1, pty);
    bilin_setup(px, px0, px1, ptx);
    bilin_setup(fy, fy0, fy1, fty);
    bilin_setup(fx, fx0, fx1, ftx);
    for (int c = tid; c < C_; c += 256) {
        const float* fp = pre_f + (size_t)(b * C_ + c) * 196;
        const float* ff = first_f + (size_t)(b * C_ + c) * 196;
        pre_q[(size_t)m * C_ + c]   = bilin_tap(fp, py0, py1, pty, px0, px1, ptx);
        first_q[(size_t)m * C_ + c] = bilin_tap(ff, fy0, fy1, fty, fx0, fx1, ftx);
    }
    if (tid < 2) curr[m * 2 + tid] = (float)prev_b[m * 2 + tid];
}

// -------------------------------------------------- K2: tokens = LN(cat)+pe
__global__ __launch_bounds__(256) void tokens_kernel(
        const float* __restrict__ curr_f, const float* __restrict__ pre_q,
        const float* __restrict__ first_q, const float* __restrict__ curr,
        const float* __restrict__ ln_g, const float* __restrict__ ln_b,
        float* __restrict__ tokens, short* __restrict__ tokens_bf) {
    int m = blockIdx.x;
    int b = m / N_;
    int n = m % N_;
    int tid = threadIdx.x;
    __shared__ float bf[C_];
    __shared__ float red[10];

    float cy = curr[m * 2], cx = curr[m * 2 + 1];
    int iy = (int)cy, ix = (int)cx;
    int y0, y1, x0, x1;
    float ty, tx;
    bilin_setup(iy, y0, y1, ty);
    bilin_setup(ix, x0, x1, tx);
    for (int c = tid; c < C_; c += 256) {
        const float* f = curr_f + (size_t)(b * C_ + c) * 196;
        bf[c] = bilin_tap(f, y0, y1, ty, x0, x1, tx);
    }
    __syncthreads();

    float s = 0.f, s2 = 0.f;
    for (int d = tid; d < D_; d += 256) {
        float v;
        if (d < C_)            v = pre_q[(size_t)m * C_ + d];
        else if (d < 2 * C_)   v = bf[d - C_];
        else if (d == 2 * C_)  v = cy;
        else if (d == 2*C_+1)  v = cx;
        else                   v = first_q[(size_t)m * C_ + (d - 2 * C_ - 2)];
        s += v; s2 += v * v;
    }
    block_reduce_2(s, s2, red);
    float mean = s / (float)D_;
    float var = s2 / (float)D_ - mean * mean;
    float inv = rsqrtf(var + EPS_);

    const float negLogDivD = -logf(10000.0f) / (float)D_;
    for (int d = tid; d < KPD_; d += 256) {
        if (d < D_) {
            float v;
            if (d < C_)            v = pre_q[(size_t)m * C_ + d];
            else if (d < 2 * C_)   v = bf[d - C_];
            else if (d == 2 * C_)  v = cy;
            else if (d == 2*C_+1)  v = cx;
            else                   v = first_q[(size_t)m * C_ + (d - 2 * C_ - 2)];
            float ln = ln_g[d] * (v - mean) * inv + ln_b[d];
            int kk = d >> 1;
            float ang = (float)n * expf((float)(2 * kk) * negLogDivD);
            float pe = (d & 1) ? cosf(ang) : sinf(ang);
            float val = ln + pe;
            tokens[(size_t)m * D_ + d] = val;
            tokens_bf[(size_t)m * KPD_ + d] = f2bf(val);
        } else {
            tokens_bf[(size_t)m * KPD_ + d] = 0;
        }
    }
}

// ---------------------------------------------- weight fp32 -> padded bf16
// one block per output row; rows zero-padded from K to Kp
__global__ __launch_bounds__(256) void wcvt_kernel(const float* __restrict__ w,
                                                   short* __restrict__ o,
                                                   int K, int Kp) {
    int r = blockIdx.x;
    const float* src = w + (size_t)r * K;
    short* dst = o + (size_t)r * Kp;
    int nv = K >> 2;       // full groups of 4
    int npv = Kp >> 2;
    for (int g = threadIdx.x; g < npv; g += 256) {
        short4 ov;
        if (g < nv) {
            float2 a = *(const float2*)(src + 4 * g);
            float2 b = *(const float2*)(src + 4 * g + 2);
            ov.x = f2bf(a.x); ov.y = f2bf(a.y);
            ov.z = f2bf(b.x); ov.w = f2bf(b.y);
        } else {
            float v0 = (4 * g     < K) ? src[4 * g]     : 0.f;
            float v1 = (4 * g + 1 < K) ? src[4 * g + 1] : 0.f;
            float v2 = (4 * g + 2 < K) ? src[4 * g + 2] : 0.f;
            float v3 = (4 * g + 3 < K) ? src[4 * g + 3] : 0.f;
            ov.x = f2bf(v0); ov.y = f2bf(v1); ov.z = f2bf(v2); ov.w = f2bf(v3);
        }
        *(short4*)(dst + 4 * g) = ov;
    }
}

// ------------------------------------------------ MFMA GEMM, bf16 W, split-K
// C[m,o] (+)= sum_k A[m,k]*W[o,k]; A [M_][Kp] bf16 zero-padded, W [O][Kp] bf16
// zero-padded. Each wave: 2 o-strips (o0, o0+16) x 10 m-tiles; block = 128 o.
// W prefetched 1 chunk ahead (long-latency stream); A loaded in-loop (L2-hot).
__global__ __launch_bounds__(256, 3) void gemm_mfma_bf(
        const short* __restrict__ A, const short* __restrict__ Wb,
        const float* __restrict__ bias, float* __restrict__ Cout,
        int Kp, int O, int KC) {
    int kc0 = blockIdx.y * KC;
    if (kc0 >= Kp) return;
    int kend = min(Kp, kc0 + KC);

    int lane = threadIdx.x & 63;
    int wave = threadIdx.x >> 6;
    int col  = lane & 15;
    int quad = lane >> 4;
    int o0 = blockIdx.x * 128 + wave * 32 + col;
    int o1 = o0 + 16;
    int oc0 = min(o0, O - 1), oc1 = min(o1, O - 1);

    const short* w0p = Wb + (size_t)oc0 * Kp + quad * 8 + kc0;
    const short* w1p = Wb + (size_t)oc1 * Kp + quad * 8 + kc0;
    const short* ap  = A  + (size_t)col * Kp + quad * 8 + kc0;

    f32x4 acc0[10], acc1[10];
#pragma unroll
    for (int t = 0; t < 10; ++t)
#pragma unroll
        for (int r = 0; r < 4; ++r) { acc0[t][r] = 0.f; acc1[t][r] = 0.f; }

    int nch = (kend - kc0) >> 5;
    bf16x8 w0c = *(const bf16x8*)(w0p);
    bf16x8 w1c = *(const bf16x8*)(w1p);
    for (int i = 0; i < nch; ++i) {
        bf16x8 w0n, w1n;
        if (i + 1 < nch) {
            w0n = *(const bf16x8*)(w0p + (i + 1) * 32);
            w1n = *(const bf16x8*)(w1p + (i + 1) * 32);
        }
#pragma unroll
        for (int t = 0; t < 10; ++t) {
            bf16x8 af = *(const bf16x8*)(ap + (size_t)t * 16 * Kp + i * 32);
            acc0[t] = __builtin_amdgcn_mfma_f32_16x16x32_bf16(af, w0c, acc0[t], 0, 0, 0);
            acc1[t] = __builtin_amdgcn_mfma_f32_16x16x32_bf16(af, w1c, acc1[t], 0, 0, 0);
        }
        w0c = w0n; w1c = w1n;
    }

    if (o0 < O) {
        float bv = (blockIdx.y == 0) ? bias[o0] : 0.f;
#pragma unroll
        for (int t = 0; t < 10; ++t)
#pragma unroll
            for (int r = 0; r < 4; ++r)
                atomicAdd(&Cout[(size_t)(t * 16 + quad * 4 + r) * O + o0], acc0[t][r] + bv);
    }
    if (o1 < O) {
        float bv = (blockIdx.y == 0) ? bias[o1] : 0.f;
#pragma unroll
        for (int t = 0; t < 10; ++t)
#pragma unroll
            for (int r = 0; r < 4; ++r)
                atomicAdd(&Cout[(size_t)(t * 16 + quad * 4 + r) * O + o1], acc1[t][r] + bv);
    }
}

// ------------------------------------------------ MFMA GEMM, fp32 W (fallback)
__global__ __launch_bounds__(256) void gemm_mfma_sk(
        const short* __restrict__ A, const float* __restrict__ Wf,
        const float* __restrict__ bias, float* __restrict__ Cout,
        int K, int KpA, int O, int KC) {
    int kc0 = blockIdx.y * KC;
    if (kc0 >= K) return;
    int kend = min(K, kc0 + KC);

    int lane = threadIdx.x & 63;
    int wave = threadIdx.x >> 6;
    int col  = lane & 15;
    int quad = lane >> 4;
    int o0 = blockIdx.x * 128 + wave * 32 + col;
    int o1 = o0 + 16;
    int oc0 = min(o0, O - 1), oc1 = min(o1, O - 1);

    const float* wrow0 = Wf + (size_t)oc0 * K + quad * 8;
    const float* wrow1 = Wf + (size_t)oc1 * K + quad * 8;
    const short* abase = A + (size_t)col * KpA + quad * 8;

    f32x4 acc0[10], acc1[10];
#pragma unroll
    for (int t = 0; t < 10; ++t)
#pragma unroll
        for (int r = 0; r < 4; ++r) { acc0[t][r] = 0.f; acc1[t][r] = 0.f; }

    int nfull = (kend - kc0) >> 5;
    bf16x8 aCur[10];
    float2 wCur[8];
    if (nfull > 0) {
#pragma unroll
        for (int t = 0; t < 10; ++t)
            aCur[t] = *(const bf16x8*)(abase + (size_t)t * 16 * KpA + kc0);
#pragma unroll
        for (int j = 0; j < 4; ++j) {
            wCur[j]     = *(const float2*)(wrow0 + kc0 + 2 * j);
            wCur[4 + j] = *(const float2*)(wrow1 + kc0 + 2 * j);
        }
    }
    for (int i = 0; i < nfull; ++i) {
        bf16x8 aNxt[10];
        float2 wNxt[8];
        if (i + 1 < nfull) {
            int kn = kc0 + (i + 1) * 32;
#pragma unroll
            for (int t = 0; t < 10; ++t)
                aNxt[t] = *(const bf16x8*)(abase + (size_t)t * 16 * KpA + kn);
#pragma unroll
            for (int j = 0; j < 4; ++j) {
                wNxt[j]     = *(const float2*)(wrow0 + kn + 2 * j);
                wNxt[4 + j] = *(const float2*)(wrow1 + kn + 2 * j);
            }
        }
        bf16x8 b0, b1;
#pragma unroll
        for (int j = 0; j < 4; ++j) {
            b0[2*j] = f2bf(wCur[j].x);     b0[2*j+1] = f2bf(wCur[j].y);
            b1[2*j] = f2bf(wCur[4+j].x);   b1[2*j+1] = f2bf(wCur[4+j].y);
        }
#pragma unroll
        for (int t = 0; t < 10; ++t) {
            acc0[t] = __builtin_amdgcn_mfma_f32_16x16x32_bf16(aCur[t], b0, acc0[t], 0, 0, 0);
            acc1[t] = __builtin_amdgcn_mfma_f32_16x16x32_bf16(aCur[t], b1, acc1[t], 0, 0, 0);
        }
#pragma unroll
        for (int t = 0; t < 10; ++t) aCur[t] = aNxt[t];
#pragma unroll
        for (int j = 0; j < 8; ++j) wCur[j] = wNxt[j];
    }
    int kmain = kc0 + nfull * 32;
    if (kmain < kend) {   // ragged tail (last split only); A is zero-padded
        bf16x8 b0, b1;
#pragma unroll
        for (int j = 0; j < 8; ++j) {
            int k = kmain + quad * 8 + j;
            b0[j] = (k < kend) ? f2bf(Wf[(size_t)oc0 * K + k]) : (short)0;
            b1[j] = (k < kend) ? f2bf(Wf[(size_t)oc1 * K + k]) : (short)0;
        }
#pragma unroll
        for (int t = 0; t < 10; ++t) {
            bf16x8 af = *(const bf16x8*)(abase + (size_t)t * 16 * KpA + kmain);
            acc0[t] = __builtin_amdgcn_mfma_f32_16x16x32_bf16(af, b0, acc0[t], 0, 0, 0);
            acc1[t] = __builtin_amdgcn_mfma_f32_16x16x32_bf16(af, b1, acc1[t], 0, 0, 0);
        }
    }
    if (o0 < O) {
        float bv = (blockIdx.y == 0) ? bias[o0] : 0.f;
#pragma unroll
        for (int t = 0; t < 10; ++t)
#pragma unroll
            for (int r = 0; r < 4; ++r)
                atomicAdd(&Cout[(size_t)(t * 16 + quad * 4 + r) * O + o0], acc0[t][r] + bv);
    }
    if (o1 < O) {
        float bv = (blockIdx.y == 0) ? bias[o1] : 0.f;
#pragma unroll
        for (int t = 0; t < 10; ++t)
#pragma unroll
            for (int r = 0; r < 4; ++r)
                atomicAdd(&Cout[(size_t)(t * 16 + quad * 4 + r) * O + o1], acc1[t][r] + bv);
    }
}

// ------------------------------------------------ relu + bf16 convert (ff1)
__global__ __launch_bounds__(256) void relu_cvt_kernel(const float* __restrict__ in,
                                                       short* __restrict__ out,
                                                       int n) {
    int i = blockIdx.x * 256 + threadIdx.x;
    if (i < n) out[i] = f2bf(fmaxf(in[i], 0.f));
}

// ---------------------------------------- qkv fp32 -> padded bf16 q/k/v
// q_bf,k_bf: [M_][KPD_]; v_bf: [B_][96][KPD_] (rows 80..95 pre-zeroed)
__global__ __launch_bounds__(256) void qkv_cvt_kernel(const float* __restrict__ qkv,
                                                      short* __restrict__ q_bf,
                                                      short* __restrict__ k_bf,
                                                      short* __restrict__ v_bf) {
    int m = blockIdx.x;
    int b = m / N_, q = m % N_;
    const float* src = qkv + (size_t)m * QKV_;
    for (int d = threadIdx.x; d < KPD_; d += 256) {
        short qv = (d < D_) ? f2bf(src[d])          : (short)0;
        short kv = (d < D_) ? f2bf(src[D_ + d])     : (short)0;
        short vv = (d < D_) ? f2bf(src[2 * D_ + d]) : (short)0;
        q_bf[(size_t)m * KPD_ + d] = qv;
        k_bf[(size_t)m * KPD_ + d] = kv;
        v_bf[((size_t)b * 96 + q) * KPD_ + d] = vv;
    }
}

// ------------------------------------------------ scores = Q·K^T via MFMA
// grid: b*25 + qt*5 + kt (50 blocks). 4 waves split the d-chunks; LDS reduce.
__global__ __launch_bounds__(256) void scores_mfma(const short* __restrict__ q_bf,
                                                   const short* __restrict__ k_bf,
                                                   float* __restrict__ sc) {
    int bi = blockIdx.x;
    int b = bi / 25, qt = (bi % 25) / 5, kt = bi % 5;
    int lane = threadIdx.x & 63, wave = threadIdx.x >> 6;
    int col = lane & 15, quad = lane >> 4;
    const short* qbase = q_bf + (size_t)(b * N_ + qt * 16 + col) * KPD_ + quad * 8;
    const short* kbase = k_bf + (size_t)(b * N_ + kt * 16 + col) * KPD_ + quad * 8;
    f32x4 acc;
#pragma unroll
    for (int r = 0; r < 4; ++r) acc[r] = 0.f;
    int c0 = wave * 25, c1 = min(97, c0 + 25);   // 97 chunks of 32 over KPD_
    for (int c = c0; c < c1; ++c) {
        bf16x8 af = *(const bf16x8*)(qbase + c * 32);
        bf16x8 bf8 = *(const bf16x8*)(kbase + c * 32);
        acc = __builtin_amdgcn_mfma_f32_16x16x32_bf16(af, bf8, acc, 0, 0, 0);
    }
    __shared__ f32x4 red[4][64];
    red[wave][lane] = acc;
    __syncthreads();
    if (threadIdx.x < 64) {
        f32x4 t = red[0][lane];
#pragma unroll
        for (int w = 1; w < 4; ++w)
#pragma unroll
            for (int r = 0; r < 4; ++r) t[r] += red[w][lane][r];
        float scale = rsqrtf((float)D_);
#pragma unroll
        for (int r = 0; r < 4; ++r)
            sc[(size_t)(b * N_ + qt * 16 + quad * 4 + r) * N_ + kt * 16 + col] = t[r] * scale;
    }
}

// ------------------------------------------------ softmax -> p_bf [M_][96]
__global__ __launch_bounds__(256) void softmax_kernel(const float* __restrict__ sc,
                                                      short* __restrict__ p_bf) {
    int m = blockIdx.x * 4 + (threadIdx.x >> 6);
    int lane = threadIdx.x & 63;
    const float* row = sc + (size_t)m * N_;
    float a = row[lane];
    float bv = (lane < 16) ? row[64 + lane] : -1e30f;
    float mx = wave_max(fmaxf(a, bv));
    mx = __shfl(mx, 0, 64);
    float e0 = expf(a - mx);
    float e1 = (lane < 16) ? expf(bv - mx) : 0.f;
    float sum = wave_sum(e0 + e1);
    sum = __shfl(sum, 0, 64);
    float rs = 1.0f / sum;
    p_bf[(size_t)m * 96 + lane] = f2bf(e0 * rs);
    if (lane < 32)
        p_bf[(size_t)m * 96 + 64 + lane] = (lane < 16) ? f2bf(e1 * rs) : (short)0;
}

// ------------------------------------------------ av = P·V via MFMA
// grid: b*49 + dgroup (98 blocks); wave w -> d-tile dgroup*4+w (194 tiles).
__global__ __launch_bounds__(256) void av_mfma(const short* __restrict__ p_bf,
                                               const short* __restrict__ v_bf,
                                               short* __restrict__ av_bf) {
    int bi = blockIdx.x;
    int b = bi / 49, g = bi % 49;
    int lane = threadIdx.x & 63, wave = threadIdx.x >> 6;
    int dtile = g * 4 + wave;
    if (dtile >= 194) return;          // no barriers below
    int d0 = dtile * 16;
    int col = lane & 15, quad = lane >> 4;
    const short* pbase = p_bf + (size_t)b * N_ * 96 + quad * 8;
    const short* vb = v_bf + (size_t)b * 96 * KPD_ + d0 + col;
    f32x4 acc[5];
#pragma unroll
    for (int t = 0; t < 5; ++t)
#pragma unroll
        for (int r = 0; r < 4; ++r) acc[t][r] = 0.f;
#pragma unroll
    for (int c = 0; c < 3; ++c) {      // K = 96 = 3 chunks of 32
        bf16x8 bf8;
#pragma unroll
        for (int j = 0; j < 8; ++j)
            bf8[j] = vb[(size_t)(c * 32 + quad * 8 + j) * KPD_];
#pragma unroll
        for (int t = 0; t < 5; ++t) {
            bf16x8 af = *(const bf16x8*)(pbase + (size_t)(t * 16 + col) * 96 + c * 32);
            acc[t] = __builtin_amdgcn_mfma_f32_16x16x32_bf16(af, bf8, acc[t], 0, 0, 0);
        }
    }
#pragma unroll
    for (int t = 0; t < 5; ++t)
#pragma unroll
        for (int r = 0; r < 4; ++r)
            av_bf[(size_t)(b * N_ + t * 16 + quad * 4 + r) * KPD_ + d0 + col] = f2bf(acc[t][r]);
}

// ---------------------------------------------------------------- layernorm
template <bool WF32>
__global__ __launch_bounds__(256) void ln_kernel(const float* __restrict__ xin,
                                                 const float* __restrict__ res,
                                                 const float* __restrict__ g,
                                                 const float* __restrict__ bta,
                                                 float* __restrict__ outf,
                                                 short* __restrict__ outb) {
    int m = blockIdx.x;
    int tid = threadIdx.x;
    __shared__ float red[10];
    const float* xr = xin + (size_t)m * D_;
    const float* rr = res + (size_t)m * D_;
    float s = 0.f, s2 = 0.f;
    for (int d = tid; d < D_; d += 256) {
        float v = xr[d] + rr[d];
        s += v; s2 += v * v;
    }
    block_reduce_2(s, s2, red);
    float mean = s / (float)D_;
    float var = s2 / (float)D_ - mean * mean;
    float inv = rsqrtf(var + EPS_);
    for (int d = tid; d < KPD_; d += 256) {
        if (d < D_) {
            float v = xr[d] + rr[d];
            float y = g[d] * (v - mean) * inv + bta[d];
            if (WF32) outf[(size_t)m * D_ + d] = y;
            outb[(size_t)m * KPD_ + d] = f2bf(y);
        } else {
            outb[(size_t)m * KPD_ + d] = 0;
        }
    }
}

// ---------------------------------------------------------------- update
__global__ __launch_bounds__(256) void update_kernel(const float* __restrict__ outb,
                                                     float* __restrict__ curr,
                                                     float* __restrict__ pre_q,
                                                     float* __restrict__ results) {
    int m = blockIdx.x;
    int tid = threadIdx.x;
    for (int c = tid; c < C_; c += 256)
        pre_q[(size_t)m * C_ + c] += outb[(size_t)m * OD_ + c];
    if (tid < 2) {
        float nc = curr[m * 2 + tid] + outb[(size_t)m * OD_ + C_ + tid];
        nc = fminf(fmaxf(nc, 0.f), 223.f);
        curr[m * 2 + tid] = nc;
        results[m * 2 + tid] = nc;
    }
}

// ---------------------------------------------------------------- launch
extern "C" void kernel_launch(void* const* d_in, const int* in_sizes, int n_in,
                              void* d_out, int out_size, void* d_ws, size_t ws_size,
                              hipStream_t stream) {
    const float* pre_f   = (const float*)d_in[0];
    const float* curr_f  = (const float*)d_in[1];
    const float* first_f = (const float*)d_in[2];
    const int*   prev_b  = (const int*)d_in[3];
    const int*   first_b = (const int*)d_in[4];
    const float* ln_g    = (const float*)d_in[5];
    const float* ln_b    = (const float*)d_in[6];
    const float* ipw     = (const float*)d_in[7];
    const float* ipb     = (const float*)d_in[8];
    const float* opw     = (const float*)d_in[9];
    const float* opb     = (const float*)d_in[10];
    const float* n1g     = (const float*)d_in[11];
    const float* n1b     = (const float*)d_in[12];
    const float* l1w     = (const float*)d_in[13];
    const float* l1b     = (const float*)d_in[14];
    const float* l2w     = (const float*)d_in[15];
    const float* l2b     = (const float*)d_in[16];
    const float* n2g     = (const float*)d_in[17];
    const float* n2b     = (const float*)d_in[18];
    const float* ow      = (const float*)d_in[19];
    const float* ob      = (const float*)d_in[20];
    float* outp = (float*)d_out;

    float* wf = (float*)d_ws;
    size_t off = 0;
    int*   fb_al   = (int*)(wf + off); off += 320;
    float* curr    = wf + off;         off += 320;
    float* pre_q   = wf + off;         off += (size_t)M_ * C_;
    float* first_q = wf + off;         off += (size_t)M_ * C_;
    float* tokens  = wf + off;         off += (size_t)M_ * D_;
    float* qkv     = wf + off;         off += (size_t)M_ * QKV_;
    float* aout    = wf + off;         off += (size_t)M_ * D_;
    float* xbuf    = wf + off;         off += (size_t)M_ * D_;
    float* ff1f    = wf + off;         off += (size_t)M_ * DFF_;
    float* ffout   = wf + off;         off += (size_t)M_ * D_;
    float* outb    = wf + off;         off += (size_t)M_ * OD_;
    float* sc      = wf + off;         off += (size_t)M_ * N_;
    short* tokens_bf = (short*)(wf + off); off += (size_t)M_ * KPD_ / 2;
    short* x_bf      = (short*)(wf + off); off += (size_t)M_ * KPD_ / 2;
    short* x2_bf     = (short*)(wf + off); off += (size_t)M_ * KPD_ / 2;
    short* av_bf     = (short*)(wf + off); off += (size_t)M_ * KPD_ / 2;
    short* ff1_bf    = (short*)(wf + off); off += (size_t)M_ * DFF_ / 2;
    short* q_bf      = (short*)(wf + off); off += (size_t)M_ * KPD_ / 2;
    short* k_bf      = (short*)(wf + off); off += (size_t)M_ * KPD_ / 2;
    short* v_bf      = (short*)(wf + off); off += (size_t)B_ * 96 * KPD_ / 2;
    short* p_bf      = (short*)(wf + off); off += (size_t)M_ * 96 / 2;
    // bf16 pre-converted weights (108 MB) — only if workspace allows
    short* ipw_bf = (short*)(wf + off); off += (size_t)QKV_ * KPD_ / 2;
    short* opw_bf = (short*)(wf + off); off += (size_t)D_ * KPD_ / 2;
    short* l1w_bf = (short*)(wf + off); off += (size_t)DFF_ * KPD_ / 2;
    short* l2w_bf = (short*)(wf + off); off += (size_t)D_ * DFF_ / 2;
    short* ow_bf  = (short*)(wf + off); off += (size_t)OD_ * KPD_ / 2;
    bool use_bf = ws_size >= off * sizeof(float);
    (void)in_sizes; (void)n_in; (void)out_size;

    hipLaunchKernelGGL(align_kernel, dim3(B_), dim3(128), 0, stream,
                       prev_b, first_b, fb_al);
    hipLaunchKernelGGL(gather_init_kernel, dim3(M_), dim3(256), 0, stream,
                       pre_f, first_f, prev_b, fb_al, pre_q, first_q, curr);
    // zero v_bf once (pad rows 80..95 must be 0; real rows overwritten each iter)
    hipMemsetAsync(v_bf, 0, (size_t)B_ * 96 * KPD_ * 2, stream);

    if (use_bf) {   // one-time fp32 -> padded-bf16 weight conversion
        hipLaunchKernelGGL(wcvt_kernel, dim3(QKV_), dim3(256), 0, stream, ipw, ipw_bf, D_, KPD_);
        hipLaunchKernelGGL(wcvt_kernel, dim3(D_),   dim3(256), 0, stream, opw, opw_bf, D_, KPD_);
        hipLaunchKernelGGL(wcvt_kernel, dim3(DFF_), dim3(256), 0, stream, l1w, l1w_bf, D_, KPD_);
        hipLaunchKernelGGL(wcvt_kernel, dim3(D_),   dim3(256), 0, stream, l2w, l2w_bf, DFF_, DFF_);
        hipLaunchKernelGGL(wcvt_kernel, dim3(OD_),  dim3(256), 0, stream, ow, ow_bf, D_, KPD_);
    }

    for (int it = 0; it < 3; ++it) {
        hipMemsetAsync(qkv,   0, (size_t)M_ * QKV_ * 4, stream);
        hipMemsetAsync(aout,  0, (size_t)M_ * D_   * 4, stream);
        hipMemsetAsync(ff1f,  0, (size_t)M_ * DFF_ * 4, stream);
        hipMemsetAsync(ffout, 0, (size_t)M_ * D_   * 4, stream);
        hipMemsetAsync(outb,  0, (size_t)M_ * OD_  * 4, stream);

        hipLaunchKernelGGL(tokens_kernel, dim3(M_), dim3(256), 0, stream,
                           curr_f, pre_q, first_q, curr, ln_g, ln_b, tokens, tokens_bf);
        // qkv: O=9222 -> 73 o-blocks x S=11 (KC=288) = 803 blocks
        if (use_bf)
            hipLaunchKernelGGL(gemm_mfma_bf, dim3(73, 11), dim3(256), 0, stream,
                               tokens_bf, ipw_bf, ipb, qkv, KPD_, QKV_, 288);
        else
            hipLaunchKernelGGL(gemm_mfma_sk, dim3(73, 6), dim3(256), 0, stream,
                               tokens_bf, ipw, ipb, qkv, D_, KPD_, QKV_, 544);
        hipLaunchKernelGGL(qkv_cvt_kernel, dim3(M_), dim3(256), 0, stream,
                           qkv, q_bf, k_bf, v_bf);
        hipLaunchKernelGGL(scores_mfma, dim3(50), dim3(256), 0, stream,
                           q_bf, k_bf, sc);
        hipLaunchKernelGGL(softmax_kernel, dim3(40), dim3(256), 0, stream,
                           sc, p_bf);
        hipLaunchKernelGGL(av_mfma, dim3(98), dim3(256), 0, stream,
                           p_bf, v_bf, av_bf);
        // out-proj: O=3074 -> 25 x S=20 (KC=160) = 500 blocks
        if (use_bf)
            hipLaunchKernelGGL(gemm_mfma_bf, dim3(25, 20), dim3(256), 0, stream,
                               av_bf, opw_bf, opb, aout, KPD_, D_, 160);
        else
            hipLaunchKernelGGL(gemm_mfma_sk, dim3(25, 10), dim3(256), 0, stream,
                               av_bf, opw, opb, aout, D_, KPD_, D_, 320);
        hipLaunchKernelGGL((ln_kernel<true>), dim3(M_), dim3(256), 0, stream,
                           tokens, aout, n1g, n1b, xbuf, x_bf);
        // ff1: O=2048 -> 16 x S=25 (KC=128) = 400 blocks
        if (use_bf)
            hipLaunchKernelGGL(gemm_mfma_bf, dim3(16, 25), dim3(256), 0, stream,
                               x_bf, l1w_bf, l1b, ff1f, KPD_, DFF_, 128);
        else
            hipLaunchKernelGGL(gemm_mfma_sk, dim3(16, 17), dim3(256), 0, stream,
                               x_bf, l1w, l1b, ff1f, D_, KPD_, DFF_, 192);
        hipLaunchKernelGGL(relu_cvt_kernel, dim3((M_ * DFF_ + 255) / 256), dim3(256), 0, stream,
                           ff1f, ff1_bf, M_ * DFF_);
        // ff2: K=2048, O=3074 -> 25 x S=16 (KC=128) = 400 blocks
        if (use_bf)
            hipLaunchKernelGGL(gemm_mfma_bf, dim3(25, 16), dim3(256), 0, stream,
                               ff1_bf, l2w_bf, l2b, ffout, DFF_, D_, 128);
        else
            hipLaunchKernelGGL(gemm_mfma_sk, dim3(25, 11), dim3(256), 0, stream,
                               ff1_bf, l2w, l2b, ffout, DFF_, DFF_, D_, 192);
        hipLaunchKernelGGL((ln_kernel<false>), dim3(M_), dim3(256), 0, stream,
                           xbuf, ffout, n2g, n2b, (float*)nullptr, x2_bf);
        // head: O=1026 -> 9 x S=25 (KC=128) = 225 blocks
        if (use_bf)
            hipLaunchKernelGGL(gemm_mfma_bf, dim3(9, 25), dim3(256), 0, stream,
                               x2_bf, ow_bf, ob, outb, KPD_, OD_, 128);
        else
            hipLaunchKernelGGL(gemm_mfma_sk, dim3(9, 13), dim3(256), 0, stream,
                               x2_bf, ow, ob, outb, D_, KPD_, OD_, 256);
        hipLaunchKernelGGL(update_kernel, dim3(M_), dim3(256), 0, stream,
                           outb, curr, pre_q, outp + (size_t)it * M_ * 2);
    }
}

// Round 2
// 1040.112 us; speedup vs baseline: 1.4584x; 1.4584x over previous
//
#include <hip/hip_runtime.h>
#include <math.h>

#define B_    2
#define C_    1024
#define N_    80
#define D_    3074
#define DFF_  2048
#define OD_   1026      // C+2
#define QKV_  9222      // 3*D
#define M_    160       // B*N token rows
#define EPS_  1e-5f
#define KPD_  3104      // D_ rounded up to multiple of 32 (bf16 row stride)

typedef __attribute__((ext_vector_type(8))) short bf16x8;   // 8 bf16 = 4 VGPRs
typedef __attribute__((ext_vector_type(4))) float f32x4;

// fp32 -> bf16 (round-to-nearest-even), bit pattern as short
__device__ inline short f2bf(float f) {
    unsigned u = __float_as_uint(f);
    u += 0x7fffu + ((u >> 16) & 1u);
    return (short)(u >> 16);
}

// ---------------------------------------------------------------- reductions
__device__ inline float wave_sum(float v) {
#pragma unroll
    for (int off = 32; off > 0; off >>= 1) v += __shfl_down(v, off, 64);
    return v;
}

__device__ inline float wave_max(float v) {
#pragma unroll
    for (int off = 32; off > 0; off >>= 1) v = fmaxf(v, __shfl_down(v, off, 64));
    return v;
}

__device__ inline void block_reduce_2(float& s, float& s2, float* red) {
    int tid = threadIdx.x;
    int lane = tid & 63, wid = tid >> 6;
    s = wave_sum(s);
    s2 = wave_sum(s2);
    if (lane == 0) { red[wid] = s; red[4 + wid] = s2; }
    __syncthreads();
    if (tid == 0) {
        red[8] = red[0] + red[1] + red[2] + red[3];
        red[9] = red[4] + red[5] + red[6] + red[7];
    }
    __syncthreads();
    s = red[8]; s2 = red[9];
}

// ---------------------------------------------------------------- bilinear
__device__ inline void bilin_setup(int p, int& i0, int& i1, float& t) {
    float s = (p + 0.5f) * 0.0625f - 0.5f;
    s = fminf(fmaxf(s, 0.0f), 13.0f);
    i0 = (int)s;
    t = s - (float)i0;
    i1 = min(i0 + 1, 13);
}

__device__ inline float bilin_tap(const float* f, int y0, int y1, float ty,
                                  int x0, int x1, float tx) {
    float a = f[y0 * 14 + x0], b = f[y0 * 14 + x1];
    float c = f[y1 * 14 + x0], d = f[y1 * 14 + x1];
    return (1.f - ty) * ((1.f - tx) * a + tx * b) + ty * ((1.f - tx) * c + tx * d);
}

// ---------------------------------------------------------------- K0: align
__global__ __launch_bounds__(128) void align_kernel(const int* __restrict__ prev_b,
                                                    const int* __restrict__ first_b,
                                                    int* __restrict__ fb_al) {
    int b = blockIdx.x;
    int tid = threadIdx.x;
    __shared__ int dist[N_];
    __shared__ int bestIdx;
    if (tid < N_) {
        int s = 0;
        for (int j = 0; j < N_; ++j) {
            int src = (j - tid) % N_;
            if (src < 0) src += N_;
            int dy = prev_b[(b * N_ + j) * 2] - first_b[(b * N_ + src) * 2];
            int dx = prev_b[(b * N_ + j) * 2 + 1] - first_b[(b * N_ + src) * 2 + 1];
            s += abs(dy) + abs(dx);
        }
        dist[tid] = s;
    }
    __syncthreads();
    if (tid == 0) {
        int best = 0, bd = dist[0];
        for (int i = 1; i < N_; ++i)
            if (dist[i] < bd) { bd = dist[i]; best = i; }
        bestIdx = best;
    }
    __syncthreads();
    if (tid < N_) {
        int src = (tid - bestIdx) % N_;
        if (src < 0) src += N_;
        fb_al[(b * N_ + tid) * 2]     = first_b[(b * N_ + src) * 2];
        fb_al[(b * N_ + tid) * 2 + 1] = first_b[(b * N_ + src) * 2 + 1];
    }
}

// -------------------------------------------------- K1: pre_q/first_q gather
__global__ __launch_bounds__(256) void gather_init_kernel(
        const float* __restrict__ pre_f, const float* __restrict__ first_f,
        const int* __restrict__ prev_b, const int* __restrict__ fb_al,
        float* __restrict__ pre_q, float* __restrict__ first_q,
        float* __restrict__ curr) {
    int m = blockIdx.x;
    int b = m / N_;
    int tid = threadIdx.x;
    int py = prev_b[m * 2], px = prev_b[m * 2 + 1];
    int fy = fb_al[m * 2], fx = fb_al[m * 2 + 1];
    int py0, py1, px0, px1, fy0, fy1, fx0, fx1;
    float pty, ptx, fty, ftx;
    bilin_setup(py, py0, py1, pty);
    bilin_setup(px, px0, px1, ptx);
    bilin_setup(fy, fy0, fy1, fty);
    bilin_setup(fx, fx0, fx1, ftx);
    for (int c = tid; c < C_; c += 256) {
        const float* fp = pre_f + (size_t)(b * C_ + c) * 196;
        const float* ff = first_f + (size_t)(b * C_ + c) * 196;
        pre_q[(size_t)m * C_ + c]   = bilin_tap(fp, py0, py1, pty, px0, px1, ptx);
        first_q[(size_t)m * C_ + c] = bilin_tap(ff, fy0, fy1, fty, fx0, fx1, ftx);
    }
    if (tid < 2) curr[m * 2 + tid] = (float)prev_b[m * 2 + tid];
}

// -------------------------------------------------- K2: tokens = LN(cat)+pe
__global__ __launch_bounds__(256) void tokens_kernel(
        const float* __restrict__ curr_f, const float* __restrict__ pre_q,
        const float* __restrict__ first_q, const float* __restrict__ curr,
        const float* __restrict__ ln_g, const float* __restrict__ ln_b,
        float* __restrict__ tokens, short* __restrict__ tokens_bf) {
    int m = blockIdx.x;
    int b = m / N_;
    int n = m % N_;
    int tid = threadIdx.x;
    __shared__ float bf[C_];
    __shared__ float red[10];

    float cy = curr[m * 2], cx = curr[m * 2 + 1];
    int iy = (int)cy, ix = (int)cx;
    int y0, y1, x0, x1;
    float ty, tx;
    bilin_setup(iy, y0, y1, ty);
    bilin_setup(ix, x0, x1, tx);
    for (int c = tid; c < C_; c += 256) {
        const float* f = curr_f + (size_t)(b * C_ + c) * 196;
        bf[c] = bilin_tap(f, y0, y1, ty, x0, x1, tx);
    }
    __syncthreads();

    float s = 0.f, s2 = 0.f;
    for (int d = tid; d < D_; d += 256) {
        float v;
        if (d < C_)            v = pre_q[(size_t)m * C_ + d];
        else if (d < 2 * C_)   v = bf[d - C_];
        else if (d == 2 * C_)  v = cy;
        else if (d == 2*C_+1)  v = cx;
        else                   v = first_q[(size_t)m * C_ + (d - 2 * C_ - 2)];
        s += v; s2 += v * v;
    }
    block_reduce_2(s, s2, red);
    float mean = s / (float)D_;
    float var = s2 / (float)D_ - mean * mean;
    float inv = rsqrtf(var + EPS_);

    const float negLogDivD = -logf(10000.0f) / (float)D_;
    for (int d = tid; d < KPD_; d += 256) {
        if (d < D_) {
            float v;
            if (d < C_)            v = pre_q[(size_t)m * C_ + d];
            else if (d < 2 * C_)   v = bf[d - C_];
            else if (d == 2 * C_)  v = cy;
            else if (d == 2*C_+1)  v = cx;
            else                   v = first_q[(size_t)m * C_ + (d - 2 * C_ - 2)];
            float ln = ln_g[d] * (v - mean) * inv + ln_b[d];
            int kk = d >> 1;
            float ang = (float)n * expf((float)(2 * kk) * negLogDivD);
            float pe = (d & 1) ? cosf(ang) : sinf(ang);
            float val = ln + pe;
            tokens[(size_t)m * D_ + d] = val;
            tokens_bf[(size_t)m * KPD_ + d] = f2bf(val);
        } else {
            tokens_bf[(size_t)m * KPD_ + d] = 0;
        }
    }
}

// ---------------------------------- weight fp32 -> MFMA-fragment-packed bf16
// Wp[((strip*nch + chunk)*64 + lane)*8 + j] = W[strip*16 + (lane&15)]
//                                              [chunk*32 + (lane>>4)*8 + j]
// A wave's B-fragment load is then ONE contiguous 1KB burst per chunk.
__global__ __launch_bounds__(256) void wpack_kernel(const float* __restrict__ w,
                                                    short* __restrict__ o,
                                                    int K, int O, int nch) {
    int s = blockIdx.x;
    int items = nch * 64;
    for (int idx = threadIdx.x; idx < items; idx += 256) {
        int c = idx >> 6, l = idx & 63;
        int col = l & 15, quad = l >> 4;
        int orow = s * 16 + col;
        int k0 = c * 32 + quad * 8;
        bf16x8 v;
        if (orow < O && k0 + 8 <= K) {
            const float* src = w + (size_t)orow * K + k0;
            float2 a = *(const float2*)(src);
            float2 b = *(const float2*)(src + 2);
            float2 cc = *(const float2*)(src + 4);
            float2 d = *(const float2*)(src + 6);
            v[0] = f2bf(a.x);  v[1] = f2bf(a.y);
            v[2] = f2bf(b.x);  v[3] = f2bf(b.y);
            v[4] = f2bf(cc.x); v[5] = f2bf(cc.y);
            v[6] = f2bf(d.x);  v[7] = f2bf(d.y);
        } else {
#pragma unroll
            for (int j = 0; j < 8; ++j) {
                int k = k0 + j;
                v[j] = (orow < O && k < K) ? f2bf(w[(size_t)orow * K + k]) : (short)0;
            }
        }
        *(bf16x8*)(o + ((size_t)s * nch + c) * 512 + l * 8) = v;
    }
}

// ------------------------------------------- MFMA GEMM on packed weights
// Block: one 16-wide o-strip x one m-group (80 rows = 5 m-tiles).
// K chunks split across the block's 4 waves -> LDS reduce -> plain store
// (atomicAdd only when gridDim.y > 1, for the small-O GEMMs).
__global__ __launch_bounds__(256) void gemm_pk(
        const short* __restrict__ A, const short* __restrict__ Wp,
        const float* __restrict__ bias, float* __restrict__ Cout,
        int KpA, int nch, int O) {
    int strip = blockIdx.x;
    int nsk = gridDim.y;
    int mg = blockIdx.z;
    int lane = threadIdx.x & 63, wave = threadIdx.x >> 6;
    int col = lane & 15, quad = lane >> 4;

    int per = (nch + nsk - 1) / nsk;
    int cs = blockIdx.y * per;
    int ce = min(nch, cs + per);
    if (cs >= ce) return;                 // uniform over block
    int tot = ce - cs;
    int qn = tot >> 2, rmd = tot & 3;
    int c0 = cs + wave * qn + min(wave, rmd);
    int c1 = c0 + qn + (wave < rmd ? 1 : 0);

    const short* wp = Wp + (size_t)strip * nch * 512 + lane * 8;
    const short* ap = A + (size_t)(mg * 80 + col) * KpA + quad * 8;

    f32x4 acc[5];
#pragma unroll
    for (int t = 0; t < 5; ++t)
#pragma unroll
        for (int r = 0; r < 4; ++r) acc[t][r] = 0.f;

    if (c0 < c1) {
        bf16x8 wcur = *(const bf16x8*)(wp + (size_t)c0 * 512);
        for (int c = c0; c < c1; ++c) {
            bf16x8 wnxt = wcur;
            if (c + 1 < c1) wnxt = *(const bf16x8*)(wp + (size_t)(c + 1) * 512);
#pragma unroll
            for (int t = 0; t < 5; ++t) {
                bf16x8 af = *(const bf16x8*)(ap + (size_t)t * 16 * KpA + c * 32);
                acc[t] = __builtin_amdgcn_mfma_f32_16x16x32_bf16(af, wcur, acc[t], 0, 0, 0);
            }
            wcur = wnxt;
        }
    }

    __shared__ f32x4 red[4][5][64];       // 20 KB
#pragma unroll
    for (int t = 0; t < 5; ++t) red[wave][t][lane] = acc[t];
    __syncthreads();
    for (int item = threadIdx.x; item < 320; item += 256) {
        int t = item >> 6, l2 = item & 63;
        f32x4 v = red[0][t][l2];
#pragma unroll
        for (int w = 1; w < 4; ++w)
#pragma unroll
            for (int r = 0; r < 4; ++r) v[r] += red[w][t][l2][r];
        int oc = strip * 16 + (l2 & 15);
        if (oc < O) {
            float bv = (blockIdx.y == 0) ? bias[oc] : 0.f;
            int rbase = mg * 80 + t * 16 + (l2 >> 4) * 4;
#pragma unroll
            for (int r = 0; r < 4; ++r) {
                float val = v[r] + bv;
                if (nsk == 1) Cout[(size_t)(rbase + r) * O + oc] = val;
                else atomicAdd(&Cout[(size_t)(rbase + r) * O + oc], val);
            }
        }
    }
}

// ------------------------------------------------ MFMA GEMM, fp32 W (fallback)
__global__ __launch_bounds__(256) void gemm_mfma_sk(
        const short* __restrict__ A, const float* __restrict__ Wf,
        const float* __restrict__ bias, float* __restrict__ Cout,
        int K, int KpA, int O, int KC) {
    int kc0 = blockIdx.y * KC;
    if (kc0 >= K) return;
    int kend = min(K, kc0 + KC);

    int lane = threadIdx.x & 63;
    int wave = threadIdx.x >> 6;
    int col  = lane & 15;
    int quad = lane >> 4;
    int o0 = blockIdx.x * 128 + wave * 32 + col;
    int o1 = o0 + 16;
    int oc0 = min(o0, O - 1), oc1 = min(o1, O - 1);

    const float* wrow0 = Wf + (size_t)oc0 * K + quad * 8;
    const float* wrow1 = Wf + (size_t)oc1 * K + quad * 8;
    const short* abase = A + (size_t)col * KpA + quad * 8;

    f32x4 acc0[10], acc1[10];
#pragma unroll
    for (int t = 0; t < 10; ++t)
#pragma unroll
        for (int r = 0; r < 4; ++r) { acc0[t][r] = 0.f; acc1[t][r] = 0.f; }

    int nfull = (kend - kc0) >> 5;
    bf16x8 aCur[10];
    float2 wCur[8];
    if (nfull > 0) {
#pragma unroll
        for (int t = 0; t < 10; ++t)
            aCur[t] = *(const bf16x8*)(abase + (size_t)t * 16 * KpA + kc0);
#pragma unroll
        for (int j = 0; j < 4; ++j) {
            wCur[j]     = *(const float2*)(wrow0 + kc0 + 2 * j);
            wCur[4 + j] = *(const float2*)(wrow1 + kc0 + 2 * j);
        }
    }
    for (int i = 0; i < nfull; ++i) {
        bf16x8 aNxt[10];
        float2 wNxt[8];
        if (i + 1 < nfull) {
            int kn = kc0 + (i + 1) * 32;
#pragma unroll
            for (int t = 0; t < 10; ++t)
                aNxt[t] = *(const bf16x8*)(abase + (size_t)t * 16 * KpA + kn);
#pragma unroll
            for (int j = 0; j < 4; ++j) {
                wNxt[j]     = *(const float2*)(wrow0 + kn + 2 * j);
                wNxt[4 + j] = *(const float2*)(wrow1 + kn + 2 * j);
            }
        }
        bf16x8 b0, b1;
#pragma unroll
        for (int j = 0; j < 4; ++j) {
            b0[2*j] = f2bf(wCur[j].x);     b0[2*j+1] = f2bf(wCur[j].y);
            b1[2*j] = f2bf(wCur[4+j].x);   b1[2*j+1] = f2bf(wCur[4+j].y);
        }
#pragma unroll
        for (int t = 0; t < 10; ++t) {
            acc0[t] = __builtin_amdgcn_mfma_f32_16x16x32_bf16(aCur[t], b0, acc0[t], 0, 0, 0);
            acc1[t] = __builtin_amdgcn_mfma_f32_16x16x32_bf16(aCur[t], b1, acc1[t], 0, 0, 0);
        }
#pragma unroll
        for (int t = 0; t < 10; ++t) aCur[t] = aNxt[t];
#pragma unroll
        for (int j = 0; j < 8; ++j) wCur[j] = wNxt[j];
    }
    int kmain = kc0 + nfull * 32;
    if (kmain < kend) {   // ragged tail (last split only); A is zero-padded
        bf16x8 b0, b1;
#pragma unroll
        for (int j = 0; j < 8; ++j) {
            int k = kmain + quad * 8 + j;
            b0[j] = (k < kend) ? f2bf(Wf[(size_t)oc0 * K + k]) : (short)0;
            b1[j] = (k < kend) ? f2bf(Wf[(size_t)oc1 * K + k]) : (short)0;
        }
#pragma unroll
        for (int t = 0; t < 10; ++t) {
            bf16x8 af = *(const bf16x8*)(abase + (size_t)t * 16 * KpA + kmain);
            acc0[t] = __builtin_amdgcn_mfma_f32_16x16x32_bf16(af, b0, acc0[t], 0, 0, 0);
            acc1[t] = __builtin_amdgcn_mfma_f32_16x16x32_bf16(af, b1, acc1[t], 0, 0, 0);
        }
    }
    if (o0 < O) {
        float bv = (blockIdx.y == 0) ? bias[o0] : 0.f;
#pragma unroll
        for (int t = 0; t < 10; ++t)
#pragma unroll
            for (int r = 0; r < 4; ++r)
                atomicAdd(&Cout[(size_t)(t * 16 + quad * 4 + r) * O + o0], acc0[t][r] + bv);
    }
    if (o1 < O) {
        float bv = (blockIdx.y == 0) ? bias[o1] : 0.f;
#pragma unroll
        for (int t = 0; t < 10; ++t)
#pragma unroll
            for (int r = 0; r < 4; ++r)
                atomicAdd(&Cout[(size_t)(t * 16 + quad * 4 + r) * O + o1], acc1[t][r] + bv);
    }
}

// ------------------------------------------------ relu + bf16 convert (ff1)
__global__ __launch_bounds__(256) void relu_cvt_kernel(const float* __restrict__ in,
                                                       short* __restrict__ out,
                                                       int n) {
    int i = blockIdx.x * 256 + threadIdx.x;
    if (i < n) out[i] = f2bf(fmaxf(in[i], 0.f));
}

// ---------------------------------------- qkv fp32 -> padded bf16 q/k/v
// q_bf,k_bf: [M_][KPD_]; v_bf: [B_][96][KPD_] (rows 80..95 pre-zeroed)
__global__ __launch_bounds__(256) void qkv_cvt_kernel(const float* __restrict__ qkv,
                                                      short* __restrict__ q_bf,
                                                      short* __restrict__ k_bf,
                                                      short* __restrict__ v_bf) {
    int m = blockIdx.x;
    int b = m / N_, q = m % N_;
    const float* src = qkv + (size_t)m * QKV_;
    for (int d = threadIdx.x; d < KPD_; d += 256) {
        short qv = (d < D_) ? f2bf(src[d])          : (short)0;
        short kv = (d < D_) ? f2bf(src[D_ + d])     : (short)0;
        short vv = (d < D_) ? f2bf(src[2 * D_ + d]) : (short)0;
        q_bf[(size_t)m * KPD_ + d] = qv;
        k_bf[(size_t)m * KPD_ + d] = kv;
        v_bf[((size_t)b * 96 + q) * KPD_ + d] = vv;
    }
}

// ------------------------------------------------ scores = Q·K^T via MFMA
// grid: b*25 + qt*5 + kt (50 blocks). 4 waves split the d-chunks; LDS reduce.
__global__ __launch_bounds__(256) void scores_mfma(const short* __restrict__ q_bf,
                                                   const short* __restrict__ k_bf,
                                                   float* __restrict__ sc) {
    int bi = blockIdx.x;
    int b = bi / 25, qt = (bi % 25) / 5, kt = bi % 5;
    int lane = threadIdx.x & 63, wave = threadIdx.x >> 6;
    int col = lane & 15, quad = lane >> 4;
    const short* qbase = q_bf + (size_t)(b * N_ + qt * 16 + col) * KPD_ + quad * 8;
    const short* kbase = k_bf + (size_t)(b * N_ + kt * 16 + col) * KPD_ + quad * 8;
    f32x4 acc;
#pragma unroll
    for (int r = 0; r < 4; ++r) acc[r] = 0.f;
    int c0 = wave * 25, c1 = min(97, c0 + 25);   // 97 chunks of 32 over KPD_
    for (int c = c0; c < c1; ++c) {
        bf16x8 af = *(const bf16x8*)(qbase + c * 32);
        bf16x8 bf8 = *(const bf16x8*)(kbase + c * 32);
        acc = __builtin_amdgcn_mfma_f32_16x16x32_bf16(af, bf8, acc, 0, 0, 0);
    }
    __shared__ f32x4 red[4][64];
    red[wave][lane] = acc;
    __syncthreads();
    if (threadIdx.x < 64) {
        f32x4 t = red[0][lane];
#pragma unroll
        for (int w = 1; w < 4; ++w)
#pragma unroll
            for (int r = 0; r < 4; ++r) t[r] += red[w][lane][r];
        float scale = rsqrtf((float)D_);
#pragma unroll
        for (int r = 0; r < 4; ++r)
            sc[(size_t)(b * N_ + qt * 16 + quad * 4 + r) * N_ + kt * 16 + col] = t[r] * scale;
    }
}

// ------------------------------------------------ softmax -> p_bf [M_][96]
__global__ __launch_bounds__(256) void softmax_kernel(const float* __restrict__ sc,
                                                      short* __restrict__ p_bf) {
    int m = blockIdx.x * 4 + (threadIdx.x >> 6);
    int lane = threadIdx.x & 63;
    const float* row = sc + (size_t)m * N_;
    float a = row[lane];
    float bv = (lane < 16) ? row[64 + lane] : -1e30f;
    float mx = wave_max(fmaxf(a, bv));
    mx = __shfl(mx, 0, 64);
    float e0 = expf(a - mx);
    float e1 = (lane < 16) ? expf(bv - mx) : 0.f;
    float sum = wave_sum(e0 + e1);
    sum = __shfl(sum, 0, 64);
    float rs = 1.0f / sum;
    p_bf[(size_t)m * 96 + lane] = f2bf(e0 * rs);
    if (lane < 32)
        p_bf[(size_t)m * 96 + 64 + lane] = (lane < 16) ? f2bf(e1 * rs) : (short)0;
}

// ------------------------------------------------ av = P·V via MFMA
// grid: b*49 + dgroup (98 blocks); wave w -> d-tile dgroup*4+w (194 tiles).
__global__ __launch_bounds__(256) void av_mfma(const short* __restrict__ p_bf,
                                               const short* __restrict__ v_bf,
                                               short* __restrict__ av_bf) {
    int bi = blockIdx.x;
    int b = bi / 49, g = bi % 49;
    int lane = threadIdx.x & 63, wave = threadIdx.x >> 6;
    int dtile = g * 4 + wave;
    if (dtile >= 194) return;          // no barriers below
    int d0 = dtile * 16;
    int col = lane & 15, quad = lane >> 4;
    const short* pbase = p_bf + (size_t)b * N_ * 96 + quad * 8;
    const short* vb = v_bf + (size_t)b * 96 * KPD_ + d0 + col;
    f32x4 acc[5];
#pragma unroll
    for (int t = 0; t < 5; ++t)
#pragma unroll
        for (int r = 0; r < 4; ++r) acc[t][r] = 0.f;
#pragma unroll
    for (int c = 0; c < 3; ++c) {      // K = 96 = 3 chunks of 32
        bf16x8 bf8;
#pragma unroll
        for (int j = 0; j < 8; ++j)
            bf8[j] = vb[(size_t)(c * 32 + quad * 8 + j) * KPD_];
#pragma unroll
        for (int t = 0; t < 5; ++t) {
            bf16x8 af = *(const bf16x8*)(pbase + (size_t)(t * 16 + col) * 96 + c * 32);
            acc[t] = __builtin_amdgcn_mfma_f32_16x16x32_bf16(af, bf8, acc[t], 0, 0, 0);
        }
    }
#pragma unroll
    for (int t = 0; t < 5; ++t)
#pragma unroll
        for (int r = 0; r < 4; ++r)
            av_bf[(size_t)(b * N_ + t * 16 + quad * 4 + r) * KPD_ + d0 + col] = f2bf(acc[t][r]);
}

// ---------------------------------------------------------------- layernorm
template <bool WF32>
__global__ __launch_bounds__(256) void ln_kernel(const float* __restrict__ xin,
                                                 const float* __restrict__ res,
                                                 const float* __restrict__ g,
                                                 const float* __restrict__ bta,
                                                 float* __restrict__ outf,
                                                 short* __restrict__ outb) {
    int m = blockIdx.x;
    int tid = threadIdx.x;
    __shared__ float red[10];
    const float* xr = xin + (size_t)m * D_;
    const float* rr = res + (size_t)m * D_;
    float s = 0.f, s2 = 0.f;
    for (int d = tid; d < D_; d += 256) {
        float v = xr[d] + rr[d];
        s += v; s2 += v * v;
    }
    block_reduce_2(s, s2, red);
    float mean = s / (float)D_;
    float var = s2 / (float)D_ - mean * mean;
    float inv = rsqrtf(var + EPS_);
    for (int d = tid; d < KPD_; d += 256) {
        if (d < D_) {
            float v = xr[d] + rr[d];
            float y = g[d] * (v - mean) * inv + bta[d];
            if (WF32) outf[(size_t)m * D_ + d] = y;
            outb[(size_t)m * KPD_ + d] = f2bf(y);
        } else {
            outb[(size_t)m * KPD_ + d] = 0;
        }
    }
}

// ---------------------------------------------------------------- update
__global__ __launch_bounds__(256) void update_kernel(const float* __restrict__ outb,
                                                     float* __restrict__ curr,
                                                     float* __restrict__ pre_q,
                                                     float* __restrict__ results) {
    int m = blockIdx.x;
    int tid = threadIdx.x;
    for (int c = tid; c < C_; c += 256)
        pre_q[(size_t)m * C_ + c] += outb[(size_t)m * OD_ + c];
    if (tid < 2) {
        float nc = curr[m * 2 + tid] + outb[(size_t)m * OD_ + C_ + tid];
        nc = fminf(fmaxf(nc, 0.f), 223.f);
        curr[m * 2 + tid] = nc;
        results[m * 2 + tid] = nc;
    }
}

// ---------------------------------------------------------------- launch
extern "C" void kernel_launch(void* const* d_in, const int* in_sizes, int n_in,
                              void* d_out, int out_size, void* d_ws, size_t ws_size,
                              hipStream_t stream) {
    const float* pre_f   = (const float*)d_in[0];
    const float* curr_f  = (const float*)d_in[1];
    const float* first_f = (const float*)d_in[2];
    const int*   prev_b  = (const int*)d_in[3];
    const int*   first_b = (const int*)d_in[4];
    const float* ln_g    = (const float*)d_in[5];
    const float* ln_b    = (const float*)d_in[6];
    const float* ipw     = (const float*)d_in[7];
    const float* ipb     = (const float*)d_in[8];
    const float* opw     = (const float*)d_in[9];
    const float* opb     = (const float*)d_in[10];
    const float* n1g     = (const float*)d_in[11];
    const float* n1b     = (const float*)d_in[12];
    const float* l1w     = (const float*)d_in[13];
    const float* l1b     = (const float*)d_in[14];
    const float* l2w     = (const float*)d_in[15];
    const float* l2b     = (const float*)d_in[16];
    const float* n2g     = (const float*)d_in[17];
    const float* n2b     = (const float*)d_in[18];
    const float* ow      = (const float*)d_in[19];
    const float* ob      = (const float*)d_in[20];
    float* outp = (float*)d_out;

    float* wf = (float*)d_ws;
    size_t off = 0;
    int*   fb_al   = (int*)(wf + off); off += 320;
    float* curr    = wf + off;         off += 320;
    float* pre_q   = wf + off;         off += (size_t)M_ * C_;
    float* first_q = wf + off;         off += (size_t)M_ * C_;
    float* tokens  = wf + off;         off += (size_t)M_ * D_;
    float* qkv     = wf + off;         off += (size_t)M_ * QKV_;
    float* aout    = wf + off;         off += (size_t)M_ * D_;
    float* xbuf    = wf + off;         off += (size_t)M_ * D_;
    float* ff1f    = wf + off;         off += (size_t)M_ * DFF_;
    float* ffout   = wf + off;         off += (size_t)M_ * D_;
    float* outb    = wf + off;         off += (size_t)M_ * OD_;
    float* sc      = wf + off;         off += (size_t)M_ * N_;
    short* tokens_bf = (short*)(wf + off); off += (size_t)M_ * KPD_ / 2;
    short* x_bf      = (short*)(wf + off); off += (size_t)M_ * KPD_ / 2;
    short* x2_bf     = (short*)(wf + off); off += (size_t)M_ * KPD_ / 2;
    short* av_bf     = (short*)(wf + off); off += (size_t)M_ * KPD_ / 2;
    short* ff1_bf    = (short*)(wf + off); off += (size_t)M_ * DFF_ / 2;
    short* q_bf      = (short*)(wf + off); off += (size_t)M_ * KPD_ / 2;
    short* k_bf      = (short*)(wf + off); off += (size_t)M_ * KPD_ / 2;
    short* v_bf      = (short*)(wf + off); off += (size_t)B_ * 96 * KPD_ / 2;
    short* p_bf      = (short*)(wf + off); off += (size_t)M_ * 96 / 2;
    // fragment-packed bf16 weights (~108 MB) — only if workspace allows.
    // strips: qkv 577, op 193, ff1 128, ff2 193, head 65; chunk counts 97/64.
    short* ipw_pk = (short*)(wf + off); off += (size_t)577 * 97 * 256;
    short* opw_pk = (short*)(wf + off); off += (size_t)193 * 97 * 256;
    short* l1w_pk = (short*)(wf + off); off += (size_t)128 * 97 * 256;
    short* l2w_pk = (short*)(wf + off); off += (size_t)193 * 64 * 256;
    short* ow_pk  = (short*)(wf + off); off += (size_t)65  * 97 * 256;
    bool use_bf = ws_size >= off * sizeof(float);
    (void)in_sizes; (void)n_in; (void)out_size;

    hipLaunchKernelGGL(align_kernel, dim3(B_), dim3(128), 0, stream,
                       prev_b, first_b, fb_al);
    hipLaunchKernelGGL(gather_init_kernel, dim3(M_), dim3(256), 0, stream,
                       pre_f, first_f, prev_b, fb_al, pre_q, first_q, curr);
    // zero v_bf once (pad rows 80..95 must be 0; real rows overwritten each iter)
    hipMemsetAsync(v_bf, 0, (size_t)B_ * 96 * KPD_ * 2, stream);

    if (use_bf) {   // one-time fp32 -> fragment-packed bf16 weight conversion
        hipLaunchKernelGGL(wpack_kernel, dim3(577), dim3(256), 0, stream, ipw, ipw_pk, D_, QKV_, 97);
        hipLaunchKernelGGL(wpack_kernel, dim3(193), dim3(256), 0, stream, opw, opw_pk, D_, D_, 97);
        hipLaunchKernelGGL(wpack_kernel, dim3(128), dim3(256), 0, stream, l1w, l1w_pk, D_, DFF_, 97);
        hipLaunchKernelGGL(wpack_kernel, dim3(193), dim3(256), 0, stream, l2w, l2w_pk, DFF_, D_, 64);
        hipLaunchKernelGGL(wpack_kernel, dim3(65),  dim3(256), 0, stream, ow, ow_pk, D_, OD_, 97);
    }

    for (int it = 0; it < 3; ++it) {
        if (!use_bf) hipMemsetAsync(qkv, 0, (size_t)M_ * QKV_ * 4, stream);
        hipMemsetAsync(aout,  0, (size_t)M_ * D_   * 4, stream);
        hipMemsetAsync(ff1f,  0, (size_t)M_ * DFF_ * 4, stream);
        hipMemsetAsync(ffout, 0, (size_t)M_ * D_   * 4, stream);
        hipMemsetAsync(outb,  0, (size_t)M_ * OD_  * 4, stream);

        hipLaunchKernelGGL(tokens_kernel, dim3(M_), dim3(256), 0, stream,
                           curr_f, pre_q, first_q, curr, ln_g, ln_b, tokens, tokens_bf);
        // qkv: 577 strips x S=1 x 2 m-groups (no atomics, direct store)
        if (use_bf)
            hipLaunchKernelGGL(gemm_pk, dim3(577, 1, 2), dim3(256), 0, stream,
                               tokens_bf, ipw_pk, ipb, qkv, KPD_, 97, QKV_);
        else
            hipLaunchKernelGGL(gemm_mfma_sk, dim3(73, 6), dim3(256), 0, stream,
                               tokens_bf, ipw, ipb, qkv, D_, KPD_, QKV_, 544);
        hipLaunchKernelGGL(qkv_cvt_kernel, dim3(M_), dim3(256), 0, stream,
                           qkv, q_bf, k_bf, v_bf);
        hipLaunchKernelGGL(scores_mfma, dim3(50), dim3(256), 0, stream,
                           q_bf, k_bf, sc);
        hipLaunchKernelGGL(softmax_kernel, dim3(40), dim3(256), 0, stream,
                           sc, p_bf);
        hipLaunchKernelGGL(av_mfma, dim3(98), dim3(256), 0, stream,
                           p_bf, v_bf, av_bf);
        // out-proj: 193 strips x S=2 x 2
        if (use_bf)
            hipLaunchKernelGGL(gemm_pk, dim3(193, 2, 2), dim3(256), 0, stream,
                               av_bf, opw_pk, opb, aout, KPD_, 97, D_);
        else
            hipLaunchKernelGGL(gemm_mfma_sk, dim3(25, 10), dim3(256), 0, stream,
                               av_bf, opw, opb, aout, D_, KPD_, D_, 320);
        hipLaunchKernelGGL((ln_kernel<true>), dim3(M_), dim3(256), 0, stream,
                           tokens, aout, n1g, n1b, xbuf, x_bf);
        // ff1: 128 strips x S=2 x 2
        if (use_bf)
            hipLaunchKernelGGL(gemm_pk, dim3(128, 2, 2), dim3(256), 0, stream,
                               x_bf, l1w_pk, l1b, ff1f, KPD_, 97, DFF_);
        else
            hipLaunchKernelGGL(gemm_mfma_sk, dim3(16, 17), dim3(256), 0, stream,
                               x_bf, l1w, l1b, ff1f, D_, KPD_, DFF_, 192);
        hipLaunchKernelGGL(relu_cvt_kernel, dim3((M_ * DFF_ + 255) / 256), dim3(256), 0, stream,
                           ff1f, ff1_bf, M_ * DFF_);
        // ff2: 193 strips x S=2 x 2 (K=2048 -> 64 chunks)
        if (use_bf)
            hipLaunchKernelGGL(gemm_pk, dim3(193, 2, 2), dim3(256), 0, stream,
                               ff1_bf, l2w_pk, l2b, ffout, DFF_, 64, D_);
        else
            hipLaunchKernelGGL(gemm_mfma_sk, dim3(25, 11), dim3(256), 0, stream,
                               ff1_bf, l2w, l2b, ffout, DFF_, DFF_, D_, 192);
        hipLaunchKernelGGL((ln_kernel<false>), dim3(M_), dim3(256), 0, stream,
                           xbuf, ffout, n2g, n2b, (float*)nullptr, x2_bf);
        // head: 65 strips x S=4 x 2
        if (use_bf)
            hipLaunchKernelGGL(gemm_pk, dim3(65, 4, 2), dim3(256), 0, stream,
                               x2_bf, ow_pk, ob, outb, KPD_, 97, OD_);
        else
            hipLaunchKernelGGL(gemm_mfma_sk, dim3(9, 13), dim3(256), 0, stream,
                               x2_bf, ow, ob, outb, D_, KPD_, OD_, 256);
        hipLaunchKernelGGL(update_kernel, dim3(M_), dim3(256), 0, stream,
                           outb, curr, pre_q, outp + (size_t)it * M_ * 2);
    }
}